// Round 4
// baseline (427.749 us; speedup 1.0000x reference)
//
#include <hip/hip_runtime.h>
#include <math.h>

#define KK 48
#define TT 1024
#define BB 512
#define START_TAG 46
#define END_TAG 47

typedef __attribute__((ext_vector_type(2))) float f32x2;

// packed fp32 FMA: acc.xy += a.xy * b.xy  (CDNA VOP3P; compiler won't emit
// v_pk_fma_f32 from scalar source, so force it)
__device__ __forceinline__ void pkfma(f32x2& acc, f32x2 a, f32x2 b) {
    asm("v_pk_fma_f32 %0, %1, %2, %0" : "+v"(acc) : "v"(a), "v"(b));
}

// ---------------------------------------------------------------------------
// Fused CRF neg-log-likelihood, one wave per sentence.
//
// Linear-domain forward recurrence: alpha'[i] = (sum_j E[i,j]*alpha[j])*ef_t[i]
// E = exp(trans) packed in 48 arch VGPRs (row i, pairs). alpha broadcast via
// LDS: one ds_write_b32 + 12 ds_read_b128 per step (same-wave DS pipe is
// in-order, single wave per block => no barrier in the loop).
//
// R2/R3 lesson: readlane/SGPR alpha loses to VALU->SALU hazards + AGPR
// eviction (VGPR_Count pinned at 32). amdgpu_waves_per_eu(1,1) — max=1 —
// is the knob that actually lifts the allocator's budget; occupancy is
// worthless here (0.5 waves/SIMD structural, chain-latency-bound).
//
// Uniform power-of-2 rescale every 4 steps, exponent ledger exact (absmax
// 0.0 in R1-R3). exp(-1e5)==0 handles START-row/END-col masking for free.
// ---------------------------------------------------------------------------
__global__ __launch_bounds__(64)
__attribute__((amdgpu_waves_per_eu(1, 1)))
void crf_kernel(const float* __restrict__ feats,
                const float* __restrict__ trans,
                const int* __restrict__ tags,
                float* __restrict__ out) {
    const int b = blockIdx.x;
    const int i = threadIdx.x;
    const int ci = (i < KK) ? i : 0;   // clamped lane->tag (avoids OOB loads)
    const float* fb = feats + (size_t)b * TT * KK;
    const int* tg = tags + b * TT;

    // ---- E row i, packed in f32x2 pairs: Epk[c] = {E[2c], E[2c+1]} ----
    f32x2 Epk[KK / 2];
    #pragma unroll
    for (int c = 0; c < KK / 2; ++c) {
        f32x2 e;
        e.x = __expf(trans[ci * KK + 2 * c]);
        e.y = __expf(trans[ci * KK + 2 * c + 1]);
        Epk[c] = e;
    }
    const float eEND = __expf(trans[END_TAG * KK + ci]);

    // ---- alpha in LDS, 64 slots (48 live + 16 junk so stores are unmasked) ----
    __shared__ __attribute__((aligned(16))) float ea_sh[64];
    ea_sh[i] = (i == START_TAG) ? 1.0f : 0.0f;
    __syncthreads();   // once, outside the loop
    const float4* ea4 = (const float4*)ea_sh;

    int esum = 0;          // exact power-of-2 scaling ledger
    float sLast = 0.0f;

    // feats prefetch: group of 4 steps, load next group while processing current
    float fr[4];
    #pragma unroll
    for (int k = 0; k < 4; ++k) fr[k] = fb[k * KK + ci];

    for (int g = 0; g < TT / 4; ++g) {
        float fn[4] = {0.f, 0.f, 0.f, 0.f};
        if (g < TT / 4 - 1) {
            #pragma unroll
            for (int k = 0; k < 4; ++k) fn[k] = fb[((g + 1) * 4 + k) * KK + ci];
        }
        // exp(feat) for current group — raw values loaded a full group ago
        float ef[4];
        #pragma unroll
        for (int k = 0; k < 4; ++k) ef[k] = __expf(fr[k]);

        #pragma unroll
        for (int k = 0; k < 4; ++k) {
            // broadcast-read previous alpha: 12 x ds_read_b128, consumed by
            // 24 v_pk_fma_f32 across 4 accumulator chains
            f32x2 acc0 = {0.f, 0.f}, acc1 = {0.f, 0.f};
            f32x2 acc2 = {0.f, 0.f}, acc3 = {0.f, 0.f};
            float ev0x = 0.0f;   // alpha_prev[0], wave-uniform (rescale probe)
            #pragma unroll
            for (int c = 0; c < 12; ++c) {
                float4 v = ea4[c];
                if (c == 0) ev0x = v.x;
                f32x2 lo, hi;
                lo.x = v.x; lo.y = v.y;
                hi.x = v.z; hi.y = v.w;
                if (c & 1) { pkfma(acc2, Epk[2 * c], lo); pkfma(acc3, Epk[2 * c + 1], hi); }
                else       { pkfma(acc0, Epk[2 * c], lo); pkfma(acc1, Epk[2 * c + 1], hi); }
            }
            f32x2 p = (acc0 + acc2) + (acc1 + acc3);
            float s = (p.x + p.y) * ef[k];

            // uniform power-of-2 rescale once per group (alpha_prev[0] > 0
            // from step 1 on; ev0x is wave-uniform)
            if (k == 1) {
                int e0 = ((__float_as_int(ev0x) >> 23) & 0xff) - 127;
                esum += e0;
                s *= __int_as_float((127 - e0) << 23);   // * 2^-e0, exact
            }
            sLast = s;
            ea_sh[i] = s;   // all 64 lanes store; slots 48-63 never read
        }
        #pragma unroll
        for (int k = 0; k < 4; ++k) fr[k] = fn[k];
    }

    // ---- gold (numerator) gather: after the hot loop so its registers and
    // load latency never touch the recurrence ----
    float gacc = 0.0f;
    #pragma unroll 4
    for (int t = i; t < TT; t += 64) {
        int cur = tg[t];
        int prev = (t == 0) ? START_TAG : tg[t - 1];
        gacc += trans[cur * KK + prev] + fb[t * KK + cur];
    }
    if (i == 0) gacc += trans[END_TAG * KK + tg[TT - 1]];

    // ---- epilogue: log_z and output ----
    float val = (i < KK) ? sLast * eEND : 0.0f;
    #pragma unroll
    for (int off = 32; off; off >>= 1) {
        val += __shfl_xor(val, off, 64);
        gacc += __shfl_xor(gacc, off, 64);
    }

    if (i == 0) {
        float logz = __logf(val) + (float)esum * 0.6931471805599453f;
        out[b] = logz - gacc;
    }
}

extern "C" void kernel_launch(void* const* d_in, const int* in_sizes, int n_in,
                              void* d_out, int out_size, void* d_ws, size_t ws_size,
                              hipStream_t stream) {
    const float* feats = (const float*)d_in[0];
    const float* trans = (const float*)d_in[1];
    const int* tags = (const int*)d_in[2];
    float* out = (float*)d_out;

    crf_kernel<<<BB, 64, 0, stream>>>(feats, trans, tags, out);
}

// Round 5
// 268.219 us; speedup vs baseline: 1.5948x; 1.5948x over previous
//
#include <hip/hip_runtime.h>
#include <math.h>

#define KK 48
#define TT 1024
#define BB 512
#define START_TAG 46
#define END_TAG 47
#define HGRP (TT / 2 / 4)   // 128 groups of 4 steps per half

// ---------------------------------------------------------------------------
// Bidirectional CRF neg-log-likelihood, TWO waves per sentence.
//
//   Z = beta_m^T * alpha_m   (exact for any split m; m = T/2)
//   alpha_t = diag(ef_t) E alpha_{t-1}        (wave 0, feats rows 0..511)
//   beta_{t-1} = E^T diag(ef_t) beta_t        (wave 1, feats rows 1023..512)
//
// Halves the 1024-long serial chain and fills all 1024 SIMDs (512 blocks x 2
// waves, 1 wave/SIMD). Inner loop is LDS-free: alpha/beta broadcast lives in
// SGPRs via 48 v_readlane per step; each v_fma reads its one allowed SGPR.
// amdgpu_waves_per_eu(1,1) (max=1!) is what actually lifts the VGPR budget
// (R4: VGPR 32->132); R2/R3's readlane test ran with E evicted to AGPRs.
//
// Uniform power-of-2 rescale every 4 steps, exact int exponent ledger
// (absmax 0.0 in R1-R4). exp(-1e5)==0 masks START-row/END-col for free.
// ---------------------------------------------------------------------------

template <bool FWD>
__device__ __forceinline__ void run_half(const float* __restrict__ fb,
                                         const float* __restrict__ trans,
                                         int ci, float& sOut, int& esumOut) {
    // E for this direction: fwd needs row ci of exp(trans), bwd needs col ci
    float Ew[KK];
    #pragma unroll
    for (int j = 0; j < KK; ++j)
        Ew[j] = __expf(FWD ? trans[ci * KK + j] : trans[j * KK + ci]);

    // lane-local state + wave-uniform broadcast state
    float s = FWD ? 0.0f : __expf(trans[END_TAG * KK + ci]);  // beta_T[ci]
    float au[KK];
    #pragma unroll
    for (int j = 0; j < KK; ++j) au[j] = (j == START_TAG) ? 1.0f : 0.0f;

    int esum = 0;

    // feats prefetch: groups of 4 rows; fwd ascending, bwd descending
    float fr[4];
    #pragma unroll
    for (int k = 0; k < 4; ++k) {
        int row = FWD ? k : (TT - 1 - k);
        fr[k] = fb[row * KK + ci];
    }

    for (int g = 0; g < HGRP; ++g) {
        float fn[4] = {0.f, 0.f, 0.f, 0.f};
        if (g < HGRP - 1) {
            #pragma unroll
            for (int k = 0; k < 4; ++k) {
                int row = FWD ? ((g + 1) * 4 + k) : (TT - 1 - (g + 1) * 4 - k);
                fn[k] = fb[row * KK + ci];
            }
        }
        // exp(feat) for current group — raw values loaded a full group ago
        float ef[4];
        #pragma unroll
        for (int k = 0; k < 4; ++k) ef[k] = __expf(fr[k]);

        #pragma unroll
        for (int k = 0; k < 4; ++k) {
            if (FWD) {
                // s_i = sum_j E[i,j] au[j];  s *= ef;  broadcast s
                float a0 = 0.f, a1 = 0.f, a2 = 0.f, a3 = 0.f;
                #pragma unroll
                for (int c = 0; c < 12; ++c) {
                    a0 = fmaf(Ew[4 * c + 0], au[4 * c + 0], a0);
                    a1 = fmaf(Ew[4 * c + 1], au[4 * c + 1], a1);
                    a2 = fmaf(Ew[4 * c + 2], au[4 * c + 2], a2);
                    a3 = fmaf(Ew[4 * c + 3], au[4 * c + 3], a3);
                }
                s = ((a0 + a1) + (a2 + a3)) * ef[k];
                if (k == 1) {   // uniform rescale; au[0] > 0 from step 1 on
                    int e0 = ((__float_as_int(au[0]) >> 23) & 0xff) - 127;
                    esum += e0;
                    s *= __int_as_float((127 - e0) << 23);
                }
                int sb = __float_as_int(s);
                #pragma unroll
                for (int j = 0; j < KK; ++j)
                    au[j] = __int_as_float(__builtin_amdgcn_readlane(sb, j));
            } else {
                // w = s*ef; broadcast w;  s_i = sum_j E[j,i] au[j]
                float w = s * ef[k];
                if (k == 1) {   // uniform rescale; au[0] > 0 from step 1 on
                    int e0 = ((__float_as_int(au[0]) >> 23) & 0xff) - 127;
                    esum += e0;
                    w *= __int_as_float((127 - e0) << 23);
                }
                int wb = __float_as_int(w);
                #pragma unroll
                for (int j = 0; j < KK; ++j)
                    au[j] = __int_as_float(__builtin_amdgcn_readlane(wb, j));
                float a0 = 0.f, a1 = 0.f, a2 = 0.f, a3 = 0.f;
                #pragma unroll
                for (int c = 0; c < 12; ++c) {
                    a0 = fmaf(Ew[4 * c + 0], au[4 * c + 0], a0);
                    a1 = fmaf(Ew[4 * c + 1], au[4 * c + 1], a1);
                    a2 = fmaf(Ew[4 * c + 2], au[4 * c + 2], a2);
                    a3 = fmaf(Ew[4 * c + 3], au[4 * c + 3], a3);
                }
                s = (a0 + a1) + (a2 + a3);
            }
        }
        #pragma unroll
        for (int k = 0; k < 4; ++k) fr[k] = fn[k];
    }
    sOut = s;        // fwd: alpha_512[lane];  bwd: beta_512[lane]
    esumOut = esum;
}

__global__ __launch_bounds__(128)
__attribute__((amdgpu_waves_per_eu(1, 1)))
void crf_kernel(const float* __restrict__ feats,
                const float* __restrict__ trans,
                const int* __restrict__ tags,
                float* __restrict__ out) {
    const int b = blockIdx.x;
    const int tid = threadIdx.x;
    const int wave = tid >> 6;          // 0 = forward, 1 = backward
    const int lane = tid & 63;
    const int ci = (lane < KK) ? lane : 0;
    const float* fb = feats + (size_t)b * TT * KK;
    const int* tg = tags + b * TT;

    __shared__ float sh[128];
    __shared__ int shE[2];
    __shared__ float shG[2];

    float sLast; int esum;
    if (wave == 0) run_half<true>(fb, trans, ci, sLast, esum);
    else           run_half<false>(fb, trans, ci, sLast, esum);

    sh[tid] = sLast;
    if (lane == 0) shE[wave] = esum;

    // ---- gold gather: 1024 t's over 128 threads, after the hot loop ----
    float gacc = 0.0f;
    #pragma unroll
    for (int r = 0; r < TT / 128; ++r) {
        int t = tid + r * 128;
        int cur = tg[t];
        int prev = (t == 0) ? START_TAG : tg[t - 1];
        gacc += trans[cur * KK + prev] + fb[t * KK + cur];
    }
    #pragma unroll
    for (int off = 32; off; off >>= 1) gacc += __shfl_xor(gacc, off, 64);
    if (lane == 0) shG[wave] = gacc;

    __syncthreads();

    if (wave == 0) {
        // Z = sum_i alpha_m[i] * beta_m[i]   (exponent ledgers add)
        float val = (lane < KK) ? sh[lane] * sh[64 + lane] : 0.0f;
        #pragma unroll
        for (int off = 32; off; off >>= 1) val += __shfl_xor(val, off, 64);
        if (lane == 0) {
            float logz = __logf(val) +
                         (float)(shE[0] + shE[1]) * 0.6931471805599453f;
            float gold = shG[0] + shG[1] + trans[END_TAG * KK + tg[TT - 1]];
            out[b] = logz - gold;
        }
    }
}

extern "C" void kernel_launch(void* const* d_in, const int* in_sizes, int n_in,
                              void* d_out, int out_size, void* d_ws, size_t ws_size,
                              hipStream_t stream) {
    const float* feats = (const float*)d_in[0];
    const float* trans = (const float*)d_in[1];
    const int* tags = (const int*)d_in[2];
    float* out = (float*)d_out;

    crf_kernel<<<BB, 128, 0, stream>>>(feats, trans, tags, out);
}